// Round 14
// baseline (1743.849 us; speedup 1.0000x reference)
//
#include <hip/hip_runtime.h>
#include <math.h>

#define B 4
#define N 1024
#define DM 512
#define H 8
#define MLP 2048
#define TOK (B * N)
#define QKVW (3 * DM)
#define EPS 1e-5f
#define SCALE 0.125f

#define PS_HN  ((long)TOK * DM)        // ln plane stride
#define PS_WQ  ((long)QKVW * DM)

using short8 = __attribute__((ext_vector_type(8))) short;
using f32x4  = __attribute__((ext_vector_type(4))) float;
using u32x4  = __attribute__((ext_vector_type(4))) unsigned int;

__device__ __forceinline__ ushort f2b(float v) {
    unsigned int u = __builtin_bit_cast(unsigned int, v);
    u += 0x7fff + ((u >> 16) & 1);   // RNE
    return (ushort)(u >> 16);
}
__device__ __forceinline__ float b2f(ushort u) {
    return __builtin_bit_cast(float, (unsigned int)u << 16);
}
// Dekker-exact 3-way bf16 split: v = h + l + q2 + O(2^-27 v)
__device__ __forceinline__ void split3(float v, ushort& h, ushort& l, ushort& q2) {
    h = f2b(v); float r1 = v - b2f(h);
    l = f2b(r1); q2 = f2b(r1 - b2f(l));
}
// split 8 fp32 into 3 bf16x8 planes and store to LDS
__device__ __forceinline__ void split_store8(f32x4 a0, f32x4 a1, char* base,
                                             int planeStride, int off) {
    short8 h8, l8, q8;
#pragma unroll
    for (int i = 0; i < 4; ++i) {
        ushort h, l, q;
        split3(a0[i], h, l, q);
        h8[i] = (short)h; l8[i] = (short)l; q8[i] = (short)q;
    }
#pragma unroll
    for (int i = 0; i < 4; ++i) {
        ushort h, l, q;
        split3(a1[i], h, l, q);
        h8[4 + i] = (short)h; l8[4 + i] = (short)l; q8[4 + i] = (short)q;
    }
    *(short8*)(base + off) = h8;
    *(short8*)(base + planeStride + off) = l8;
    *(short8*)(base + 2 * planeStride + off) = q8;
}

// ---------- LayerNorm fp32 -> 3 bf16 planes (standalone, layer 0 only) -----
__global__ __launch_bounds__(256) void ln3_kernel(const float* __restrict__ x,
                                                  const float* __restrict__ g,
                                                  const float* __restrict__ bta,
                                                  ushort* __restrict__ out) {
    const int row = blockIdx.x;
    const int t = threadIdx.x;
    const float* xr = x + (size_t)row * DM;
    float v0 = xr[t], v1 = xr[t + 256];
    float s = v0 + v1, ss = v0 * v0 + v1 * v1;
    for (int o = 32; o; o >>= 1) {
        s += __shfl_down(s, o);
        ss += __shfl_down(ss, o);
    }
    __shared__ float ls[4], lss[4];
    const int wid = t >> 6, lane = t & 63;
    if (lane == 0) { ls[wid] = s; lss[wid] = ss; }
    __syncthreads();
    if (t == 0) {
        float S = ls[0] + ls[1] + ls[2] + ls[3];
        float SS = lss[0] + lss[1] + lss[2] + lss[3];
        float mu = S / DM;
        ls[0] = mu;
        lss[0] = SS / DM - mu * mu;
    }
    __syncthreads();
    const float mu = ls[0];
    const float r = rsqrtf(lss[0] + EPS);
    float o0 = (v0 - mu) * r * g[t] + bta[t];
    float o1 = (v1 - mu) * r * g[t + 256] + bta[t + 256];
    ushort h, l, q;
    size_t i0 = (size_t)row * DM + t;
    split3(o0, h, l, q);
    out[i0] = h; out[i0 + PS_HN] = l; out[i0 + 2 * PS_HN] = q;
    split3(o1, h, l, q);
    out[i0 + 256] = h; out[i0 + 256 + PS_HN] = l; out[i0 + 256 + 2 * PS_HN] = q;
}

// ---------- fused: split-K reduce + bias + residual(+tanh) + LN -> planes --
template <int KS, bool TANH>
__global__ __launch_bounds__(256) void redln_kernel(
    const float* __restrict__ P, long pstride, const float* __restrict__ bias,
    const float* __restrict__ X, float* __restrict__ Xout,
    const float* __restrict__ g, const float* __restrict__ bta,
    ushort* __restrict__ out) {
    const int row = blockIdx.x;
    const int t = threadIdx.x;
    const size_t e0 = (size_t)row * DM + t;
    const size_t e1 = e0 + 256;
    float a0 = P[e0], a1 = P[e1];
#pragma unroll
    for (int k = 1; k < KS; ++k) {
        a0 += P[(size_t)k * pstride + e0];
        a1 += P[(size_t)k * pstride + e1];
    }
    float v0 = X[e0] + a0 + bias[t];
    float v1 = X[e1] + a1 + bias[t + 256];
    if (TANH) { v0 = tanhf(v0); v1 = tanhf(v1); }
    Xout[e0] = v0;
    Xout[e1] = v1;
    float s = v0 + v1, ss = v0 * v0 + v1 * v1;
    for (int o = 32; o; o >>= 1) {
        s += __shfl_down(s, o);
        ss += __shfl_down(ss, o);
    }
    __shared__ float ls[4], lss[4];
    const int wid = t >> 6, lane = t & 63;
    if (lane == 0) { ls[wid] = s; lss[wid] = ss; }
    __syncthreads();
    if (t == 0) {
        float S = ls[0] + ls[1] + ls[2] + ls[3];
        float SS = lss[0] + lss[1] + lss[2] + lss[3];
        float mu = S / DM;
        ls[0] = mu;
        lss[0] = SS / DM - mu * mu;
    }
    __syncthreads();
    const float mu = ls[0];
    const float r = rsqrtf(lss[0] + EPS);
    float o0 = (v0 - mu) * r * g[t] + bta[t];
    float o1 = (v1 - mu) * r * g[t + 256] + bta[t + 256];
    ushort h, l, q;
    split3(o0, h, l, q);
    out[e0] = h; out[e0 + PS_HN] = l; out[e0 + 2 * PS_HN] = q;
    split3(o1, h, l, q);
    out[e1] = h; out[e1 + PS_HN] = l; out[e1 + 2 * PS_HN] = q;
}

// ---------- transpose weights: W[K][Nn] fp32 -> 3 bf16 planes of W^T[Nn][K] -
__global__ __launch_bounds__(256) void wtrans_kernel(const float* __restrict__ W,
                                                     ushort* __restrict__ WT,
                                                     int K, int Nn, long ps) {
    __shared__ float ts[32][33];
    const int n0 = blockIdx.x * 32, k0 = blockIdx.y * 32;
    const int tx = threadIdx.x & 31, ty = threadIdx.x >> 5;
#pragma unroll
    for (int p = 0; p < 4; ++p)
        ts[ty + p * 8][tx] = W[(size_t)(k0 + ty + p * 8) * Nn + n0 + tx];
    __syncthreads();
#pragma unroll
    for (int p = 0; p < 4; ++p) {
        float v = ts[tx][ty + p * 8];
        ushort h, l, q;
        split3(v, h, l, q);
        size_t idx = (size_t)(n0 + ty + p * 8) * K + k0 + tx;
        WT[idx] = h;
        WT[idx + ps] = l;
        WT[idx + 2 * ps] = q;
    }
}

// ---------- transpose V fp32 [4096][512] -> VTf fp32 [(b*H+h)*64+d][N] -----
__global__ __launch_bounds__(256) void vtrans_kernel(const float* __restrict__ v,
                                                     float* __restrict__ vt) {
    const int z = blockIdx.z, b = z >> 3, h = z & 7;
    __shared__ float ts[32][33];
    const int j0 = blockIdx.x * 32, d0 = blockIdx.y * 32;
    const int tx = threadIdx.x & 31, ty = threadIdx.x >> 5;
#pragma unroll
    for (int p = 0; p < 4; ++p)
        ts[ty + p * 8][tx] =
            v[(size_t)(b * N + j0 + ty + p * 8) * DM + h * 64 + d0 + tx];
    __syncthreads();
#pragma unroll
    for (int p = 0; p < 4; ++p)
        vt[(size_t)((b * H + h) * 64 + d0 + ty + p * 8) * N + j0 + tx] =
            ts[tx][ty + p * 8];
}

// ---------- 3-plane split MFMA GEMM (fp32-equivalent precision) ------------
// C = A[M,K] @ (Bt[Nn,K])^T. A/B pre-split 3-plane bf16 or fp32 with on-the-
// fly Dekker split (AF32/BF32). 6 MFMA terms, small first.
// z decomposes: zo = z/ZDIV (A/B/C-outer offsets), zk = z%ZDIV (k-chunk;
// partials at zk*zCk). AKS>1 (AF32 only): A = sum of AKS fp32 chunks at
// stride aksA (ascending k), summed before the Dekker split.
// EPI: 0 plain->f32, 1 scale->f32, 2 bias+gelu->f32, 3 qkv col-branch->f32
template <int BM, int BN, int WR, int WC, int EPI, bool AF32, bool BF32,
          int ZDIV, int AKS = 1>
__global__ __launch_bounds__(256) void mm3_kernel(
    const void* __restrict__ Av, int sA, long pA, long zA,
    const void* __restrict__ Bv, int sB, long pB, long zB,
    const float* __restrict__ bias, const float* __restrict__ res,
    void* __restrict__ Cv, int sC, long zC, long zCk, long aksA,
    int K, float scale) {
    constexpr int WM = BM / WR, WN = BN / WC;
    constexpr int FM = WM / 16, FN = WN / 16;
    constexpr int RA = BM / 64, RB = BN / 64;
    static_assert(!AF32 || RA <= 2, "AF32 assumes BM<=128");
    static_assert(!BF32 || RB <= 2, "BF32 assumes BN<=128");
    static_assert(AKS == 1 || AF32, "AKS>1 requires AF32");
    int bx, by, z;
    {
        const int gx = gridDim.x, gy = gridDim.y;
        const long nwg = (long)gx * gy * gridDim.z;
        long o = ((long)blockIdx.z * gy + blockIdx.y) * gx + blockIdx.x;
        if ((nwg & 7) == 0) { const long q = nwg >> 3; o = (o & 7) * q + (o >> 3); }
        bx = (int)(o % gx);
        const long r1 = o / gx;
        by = (int)(r1 % gy);
        z  = (int)(r1 / gy);
    }
    const int zo = z / ZDIV, zk = z % ZDIV;
    const ushort* A  = AF32 ? nullptr : (const ushort*)Av + (size_t)zo * zA;
    const float*  Af = AF32 ? (const float*)Av + (size_t)zo * zA : nullptr;
    const ushort* Bt = BF32 ? nullptr : (const ushort*)Bv + (size_t)zo * zB;
    const float*  Bf = BF32 ? (const float*)Bv + (size_t)zo * zB : nullptr;
    __shared__ char lds[3 * (BM + BN) * 64];
    char* Bbase = lds + 3 * BM * 64;
    const int t = threadIdx.x;
    const int lane = t & 63, w = t >> 6;
    const int wr = w / WC, wc = w % WC;
    const int m0 = by * BM, n0 = bx * BN;
    const int sr = t >> 2, skg = t & 3;
    const int off0 = sr * 64 + 16 * (skg ^ ((sr >> 1) & 3));

    f32x4 acc[FM][FN];
#pragma unroll
    for (int i = 0; i < FM; ++i)
#pragma unroll
        for (int j = 0; j < FN; ++j) acc[i][j] = (f32x4){0.f, 0.f, 0.f, 0.f};

    u32x4 cA[3][RA], nA[3][RA], cB[3][RB], nB[3][RB];
    f32x4 cAf[2 * RA], nAf[2 * RA], cBf[2 * RB], nBf[2 * RB];

    auto loadAll = [&](int KT, u32x4 (&DA)[3][RA], f32x4 (&DAf)[2 * RA],
                       u32x4 (&DB)[3][RB], f32x4 (&DBf)[2 * RB]) {
        if constexpr (AF32) {
#pragma unroll
            for (int p = 0; p < RA; ++p) {
                const float* s_ = Af + (size_t)(m0 + sr + p * 64) * sA + KT + skg * 8;
                f32x4 v0 = *(const f32x4*)s_;
                f32x4 v1 = *(const f32x4*)(s_ + 4);
#pragma unroll
                for (int kk = 1; kk < AKS; ++kk) {
                    const float* s2 = s_ + (size_t)kk * aksA;
                    f32x4 w0 = *(const f32x4*)s2;
                    f32x4 w1 = *(const f32x4*)(s2 + 4);
#pragma unroll
                    for (int i = 0; i < 4; ++i) { v0[i] += w0[i]; v1[i] += w1[i]; }
                }
                DAf[2 * p] = v0;
                DAf[2 * p + 1] = v1;
            }
        } else {
#pragma unroll
            for (int pl = 0; pl < 3; ++pl)
#pragma unroll
                for (int p = 0; p < RA; ++p)
                    DA[pl][p] = *(const u32x4*)(A + (size_t)pl * pA +
                        (size_t)(m0 + sr + p * 64) * sA + KT + skg * 8);
        }
        if constexpr (BF32) {
#pragma unroll
            for (int p = 0; p < RB; ++p) {
                const float* s_ = Bf + (size_t)(n0 + sr + p * 64) * sB + KT + skg * 8;
                DBf[2 * p] = *(const f32x4*)s_;
                DBf[2 * p + 1] = *(const f32x4*)(s_ + 4);
            }
        } else {
#pragma unroll
            for (int pl = 0; pl < 3; ++pl)
#pragma unroll
                for (int p = 0; p < RB; ++p)
                    DB[pl][p] = *(const u32x4*)(Bt + (size_t)pl * pB +
                        (size_t)(n0 + sr + p * 64) * sB + KT + skg * 8);
        }
    };
    auto storeAll = [&](u32x4 (&DA)[3][RA], f32x4 (&DAf)[2 * RA],
                        u32x4 (&DB)[3][RB], f32x4 (&DBf)[2 * RB]) {
        if constexpr (AF32) {
#pragma unroll
            for (int p = 0; p < RA; ++p)
                split_store8(DAf[2 * p], DAf[2 * p + 1], lds, BM * 64,
                             p * 4096 + off0);
        } else {
#pragma unroll
            for (int pl = 0; pl < 3; ++pl)
#pragma unroll
                for (int p = 0; p < RA; ++p)
                    *(u32x4*)(lds + pl * BM * 64 + p * 4096 + off0) = DA[pl][p];
        }
        if constexpr (BF32) {
#pragma unroll
            for (int p = 0; p < RB; ++p)
                split_store8(DBf[2 * p], DBf[2 * p + 1], Bbase, BN * 64,
                             p * 4096 + off0);
        } else {
#pragma unroll
            for (int pl = 0; pl < 3; ++pl)
#pragma unroll
                for (int p = 0; p < RB; ++p)
                    *(u32x4*)(Bbase + pl * BN * 64 + p * 4096 + off0) = DB[pl][p];
        }
    };

    const int Kc = K / ZDIV;
    const int kbeg = zk * Kc;
    loadAll(kbeg, cA, cAf, cB, cBf);
    for (int kt = kbeg; kt < kbeg + Kc; kt += 32) {
        __syncthreads();
        storeAll(cA, cAf, cB, cBf);
        if (kt + 32 < kbeg + Kc) loadAll(kt + 32, nA, nAf, nB, nBf);
        __syncthreads();
        short8 af[3][FM], bf[3][FN];
        const int kg = lane >> 4;
#pragma unroll
        for (int pl = 0; pl < 3; ++pl)
#pragma unroll
            for (int i = 0; i < FM; ++i) {
                const int r = wr * WM + i * 16 + (lane & 15);
                af[pl][i] = *(const short8*)(lds + pl * BM * 64 + r * 64 +
                                             16 * (kg ^ ((r >> 1) & 3)));
            }
#pragma unroll
        for (int pl = 0; pl < 3; ++pl)
#pragma unroll
            for (int j = 0; j < FN; ++j) {
                const int r = wc * WN + j * 16 + (lane & 15);
                bf[pl][j] = *(const short8*)(Bbase + pl * BN * 64 + r * 64 +
                                             16 * (kg ^ ((r >> 1) & 3)));
            }
        // small terms first: s=2 (hq,ll,qh), s=1 (hl,lh), s=0 (hh)
#pragma unroll
        for (int i = 0; i < FM; ++i)
#pragma unroll
            for (int j = 0; j < FN; ++j)
#pragma unroll
                for (int s = 2; s >= 0; --s)
#pragma unroll
                    for (int ph = 0; ph <= 2; ++ph) {
                        const int pb = s - ph;
                        if (pb < 0 || pb > 2) continue;
                        acc[i][j] = __builtin_amdgcn_mfma_f32_16x16x32_bf16(
                            af[ph][i], bf[pb][j], acc[i][j], 0, 0, 0);
                    }
        if constexpr (AF32) {
#pragma unroll
            for (int p = 0; p < 2 * RA; ++p) cAf[p] = nAf[p];
        } else {
#pragma unroll
            for (int pl = 0; pl < 3; ++pl)
#pragma unroll
                for (int p = 0; p < RA; ++p) cA[pl][p] = nA[pl][p];
        }
        if constexpr (BF32) {
#pragma unroll
            for (int p = 0; p < 2 * RB; ++p) cBf[p] = nBf[p];
        } else {
#pragma unroll
            for (int pl = 0; pl < 3; ++pl)
#pragma unroll
                for (int p = 0; p < RB; ++p) cB[pl][p] = nB[pl][p];
        }
    }
    float* Cbase = (float*)Cv + (size_t)zo * zC + (size_t)zk * zCk;
#pragma unroll
    for (int i = 0; i < FM; ++i) {
#pragma unroll
        for (int j = 0; j < FN; ++j) {
            const int col = n0 + wc * WN + j * 16 + (lane & 15);
#pragma unroll
            for (int r4 = 0; r4 < 4; ++r4) {
                const int row = m0 + wr * WM + i * 16 + (lane >> 4) * 4 + r4;
                float v = acc[i][j][r4];
                if (EPI == 1) v *= scale;
                if (EPI == 2) {
                    v += bias[col];
                    v = 0.5f * v * (1.0f + erff(v * 0.70710678118654752f));
                }
                if (EPI == 3) {
                    if (col < 1024)
                        ((float*)Cv)[(size_t)row * 1024 + col] = v;
                    else
                        const_cast<float*>(res)[(size_t)row * 512 + col - 1024] = v;
                } else {
                    Cbase[(size_t)row * sC + col] = v;
                }
            }
        }
    }
}

// ---------- partial reduce: MODE 2: out = tanh(X + ΣP + bias) --------------
template <int KS, int MODE>
__global__ __launch_bounds__(256) void red_kernel(const float* __restrict__ P,
                                                  long pstride,
                                                  const float* __restrict__ bias,
                                                  const float* __restrict__ X,
                                                  float* __restrict__ out) {
    const size_t e = ((size_t)blockIdx.x * 256 + threadIdx.x) * 4;
    f32x4 a = *(const f32x4*)(P + e);
#pragma unroll
    for (int k = 1; k < KS; ++k) {
        f32x4 pk = *(const f32x4*)(P + (size_t)k * pstride + e);
#pragma unroll
        for (int i = 0; i < 4; ++i) a[i] += pk[i];
    }
    if (MODE >= 1) {
        f32x4 xb = *(const f32x4*)(X + e);
        f32x4 bb = *(const f32x4*)(bias + (e & (DM - 1)));
#pragma unroll
        for (int i = 0; i < 4; ++i) {
            float r = xb[i] + a[i] + bb[i];
            a[i] = (MODE == 2) ? tanhf(r) : r;
        }
    }
    *(f32x4*)(out + e) = a;
}

// ---------- softmax (max-subtract) + head mix + head-LN, fp32, vectorized --
__global__ __launch_bounds__(256) void softmax_mix_kernel(float* __restrict__ d,
                                                          const float* __restrict__ rw,
                                                          const float* __restrict__ rg,
                                                          const float* __restrict__ rb) {
    const int i = blockIdx.x;
    const int t = threadIdx.x;
    const int lane = t & 63, wid = t >> 6;
    __shared__ float red[4];
    __shared__ float srw[64], srg[8], srb[8];
    if (t < 64) srw[t] = rw[t];
    if (t < 8) { srg[t] = rg[t]; srb[t] = rb[t]; }
    f32x4 p[8];
#pragma unroll
    for (int h = 0; h < 8; ++h) {
        p[h] = ((const f32x4*)(d + ((size_t)h * 1024 + i) * 1024))[t];
        float lm = fmaxf(fmaxf(p[h][0], p[h][1]), fmaxf(p[h][2], p[h][3]));
        for (int o = 32; o; o >>= 1) lm = fmaxf(lm, __shfl_down(lm, o));
        __syncthreads();
        if (lane == 0) red[wid] = lm;
        __syncthreads();
        const float M = fmaxf(fmaxf(red[0], red[1]), fmaxf(red[2], red[3]));
        float ls = 0.f;
#pragma unroll
        for (int u = 0; u < 4; ++u) {
            p[h][u] = expf(p[h][u] - M);
            ls += p[h][u];
        }
        for (int o = 32; o; o >>= 1) ls += __shfl_down(ls, o);
        __syncthreads();
        if (lane == 0) red[wid] = ls;
        __syncthreads();
        const float inv = 1.0f / (red[0] + red[1] + red[2] + red[3]);
#pragma unroll
        for (int u = 0; u < 4; ++u) p[h][u] *= inv;
    }
    f32x4 mg[8];
#pragma unroll
    for (int g = 0; g < 8; ++g) {
#pragma unroll
        for (int u = 0; u < 4; ++u) {
            float acc = 0.f;
#pragma unroll
            for (int h = 0; h < 8; ++h) acc += p[h][u] * srw[h * 8 + g];
            mg[g][u] = acc;
        }
    }
#pragma unroll
    for (int u = 0; u < 4; ++u) {
        float mean = 0.f;
#pragma unroll
        for (int g = 0; g < 8; ++g) mean += mg[g][u];
        mean *= 0.125f;
        float var = 0.f;
#pragma unroll
        for (int g = 0; g < 8; ++g) { float dd = mg[g][u] - mean; var += dd * dd; }
        var *= 0.125f;
        const float rs = rsqrtf(var + EPS);
#pragma unroll
        for (int g = 0; g < 8; ++g) mg[g][u] = (mg[g][u] - mean) * rs * srg[g] + srb[g];
    }
#pragma unroll
    for (int g = 0; g < 8; ++g)
        ((f32x4*)(d + ((size_t)g * 1024 + i) * 1024))[t] = mg[g];
}

extern "C" void kernel_launch(void* const* d_in, const int* in_sizes, int n_in,
                              void* d_out, int out_size, void* d_ws, size_t ws_size,
                              hipStream_t stream) {
    const float* x_in  = (const float*)d_in[0];
    const float* ln1_g = (const float*)d_in[1];
    const float* ln1_b = (const float*)d_in[2];
    const float* w_qkv = (const float*)d_in[3];
    const float* re_w  = (const float*)d_in[4];
    const float* rln_g = (const float*)d_in[5];
    const float* rln_b = (const float*)d_in[6];
    const float* w_out = (const float*)d_in[7];
    const float* b_out = (const float*)d_in[8];
    const float* ln2_g = (const float*)d_in[9];
    const float* ln2_b = (const float*)d_in[10];
    const float* w1    = (const float*)d_in[11];
    const float* b1    = (const float*)d_in[12];
    const float* w2    = (const float*)d_in[13];
    const float* b2    = (const float*)d_in[14];

    // 80 MB, phase-aliased (byte-exact extents in MB):
    // X[0,8) QKf[8,24) VTf[24,32) D[32,64) PVP[64,80) (chunk-major [2][4096][512])
    // HN3[48,60) (ln1 planes; live from redln/ln3 until qkv reads it)
    // WQT[40,44.5) (attn transient; dead before D's b-loop writes cover it)
    // Vf[32,40) (dead after vtrans) WOT[32,33.5) OPP[34,50) (post-b-loop)
    // HN3f[8,20) W1T[20,26) W2T[40,46) HIDf[48,80) FPP[8,40) (ffn phase)
    char* wsb = (char*)d_ws;
    float*  X    = (float*)wsb;
    float*  QKf  = (float*)(wsb + (8ull << 20));
    ushort* HN3f = (ushort*)(wsb + (8ull  << 20));
    float*  FPP  = (float*)(wsb + (8ull  << 20));
    ushort* W1T  = (ushort*)(wsb + (20ull << 20));
    float*  VTf  = (float*)(wsb + (24ull << 20));
    float*  D    = (float*)(wsb + (32ull << 20));
    float*  Vf   = (float*)(wsb + (32ull << 20));
    ushort* WOT  = (ushort*)(wsb + (32ull << 20));
    float*  OPP  = (float*)(wsb + (34ull << 20));
    ushort* W2T  = (ushort*)(wsb + (40ull << 20));
    ushort* WQT  = (ushort*)(wsb + (40ull << 20));   // [40, 44.5)
    ushort* HN3  = (ushort*)(wsb + (48ull << 20));
    float*  HIDf = (float*)(wsb + (48ull << 20));
    float*  PVP  = (float*)(wsb + (64ull << 20));    // [64, 80): 2 x 4096 x 512 f32

    hipMemcpyAsync(X, x_in, sizeof(float) * (size_t)TOK * DM,
                   hipMemcpyDeviceToDevice, stream);

    for (int l = 0; l < 4; ++l) {
        // ======== attention ========
        if (l == 0)
            ln3_kernel<<<TOK, 256, 0, stream>>>(X, ln1_g, ln1_b, HN3);
        wtrans_kernel<<<dim3(QKVW / 32, DM / 32), 256, 0, stream>>>(
            w_qkv + (size_t)l * DM * QKVW, WQT, DM, QKVW, PS_WQ);
        // qkv -> QKf [4096][1024] + Vf [4096][512], fp32
        mm3_kernel<128, 128, 2, 2, 3, false, false, 1>
            <<<dim3(12, TOK / 128, 1), 256, 0, stream>>>(
            HN3, DM, PS_HN, 0, WQT, DM, PS_WQ, 0, nullptr, Vf,
            QKf, 1024, 0, 0, 0, DM, 1.f);
        vtrans_kernel<<<dim3(N / 32, 2, B * H), 256, 0, stream>>>(Vf, VTf);

        for (int b = 0; b < B; ++b) {
            const float* qb = QKf + (size_t)b * N * 1024;
            // dots (scaled) -> D [H][1024][1024] fp32; 64x64 tiles, z = head
            mm3_kernel<64, 64, 2, 2, 1, true, true, 1>
                <<<dim3(16, 16, H), 256, 0, stream>>>(
                qb, 1024, 0, 64, qb + 512, 1024, 0, 64, nullptr, nullptr,
                D, 1024, (long)1024 * 1024, 0, 0, 64, SCALE);
            softmax_mix_kernel<<<N, 256, 0, stream>>>(
                D, re_w + l * H * H, rln_g + l * H, rln_b + l * H);
            // PV 64x64 split-K x2 -> PVP[chunk][b*1024+row][head*64+col]
            mm3_kernel<64, 64, 2, 2, 0, true, true, 2>
                <<<dim3(1, 16, H * 2), 256, 0, stream>>>(
                D, 1024, 0, (long)1024 * 1024,
                VTf + (size_t)b * H * 64 * N, 1024, 0, (long)64 * N,
                nullptr, nullptr,
                PVP + (size_t)b * N * DM, DM, 64, (long)TOK * DM, 0, N, 1.f);
        }
        // out-proj (A = PVP chunk0+chunk1, split-K 2) -> OPP, then fused
        // X += OPP+bias & ln2 -> HN3f
        wtrans_kernel<<<dim3(DM / 32, DM / 32), 256, 0, stream>>>(
            w_out + (size_t)l * DM * DM, WOT, DM, DM, (long)DM * DM);
        mm3_kernel<64, 128, 1, 4, 0, true, false, 2, 2>
            <<<dim3(4, TOK / 64, 2), 256, 0, stream>>>(
            PVP, DM, 0, 0, WOT, DM, (long)DM * DM, 0, nullptr, nullptr,
            OPP, DM, 0, (long)TOK * DM, (long)TOK * DM, DM, 1.f);
        redln_kernel<2, false><<<TOK, 256, 0, stream>>>(
            OPP, (long)TOK * DM, b_out + l * DM, X, X,
            ln2_g + l * DM, ln2_b + l * DM, HN3f);

        // ======== ffn ========
        wtrans_kernel<<<dim3(MLP / 32, DM / 32), 256, 0, stream>>>(
            w1 + (size_t)l * DM * MLP, W1T, DM, MLP, (long)MLP * DM);
        mm3_kernel<128, 128, 2, 2, 2, false, false, 1>
            <<<dim3(MLP / 128, TOK / 128, 1), 256, 0, stream>>>(
            HN3f, DM, PS_HN, 0, W1T, DM, (long)MLP * DM, 0, b1 + l * MLP, nullptr,
            HIDf, MLP, 0, 0, 0, DM, 1.f);
        wtrans_kernel<<<dim3(DM / 32, MLP / 32), 256, 0, stream>>>(
            w2 + (size_t)l * MLP * DM, W2T, MLP, DM, (long)DM * MLP);
        // ffn2 split-K 4 -> FPP
        mm3_kernel<128, 128, 2, 2, 0, true, false, 4>
            <<<dim3(4, TOK / 128, 4), 256, 0, stream>>>(
            HIDf, MLP, 0, 0, W2T, MLP, (long)DM * MLP, 0, nullptr, nullptr,
            FPP, DM, 0, (long)TOK * DM, 0, MLP, 1.f);
        if (l < 3) {
            // fused: X = tanh(X + ΣFPP + bias) & ln1(l+1) -> HN3
            redln_kernel<4, true><<<TOK, 256, 0, stream>>>(
                FPP, (long)TOK * DM, b2 + l * DM, X, X,
                ln1_g + (l + 1) * DM, ln1_b + (l + 1) * DM, HN3);
        } else {
            red_kernel<4, 2><<<TOK * DM / 1024, 256, 0, stream>>>(
                FPP, (long)TOK * DM, b2 + l * DM, X, (float*)d_out);
        }
    }
}

// Round 15
// 1707.126 us; speedup vs baseline: 1.0215x; 1.0215x over previous
//
#include <hip/hip_runtime.h>
#include <math.h>

#define B 4
#define N 1024
#define DM 512
#define H 8
#define MLP 2048
#define TOK (B * N)
#define QKVW (3 * DM)
#define EPS 1e-5f
#define SCALE 0.125f

#define PS_HN  ((long)TOK * DM)        // ln plane stride
#define PS_WQ  ((long)QKVW * DM)

using short8 = __attribute__((ext_vector_type(8))) short;
using f32x4  = __attribute__((ext_vector_type(4))) float;
using u32x4  = __attribute__((ext_vector_type(4))) unsigned int;

__device__ __forceinline__ ushort f2b(float v) {
    unsigned int u = __builtin_bit_cast(unsigned int, v);
    u += 0x7fff + ((u >> 16) & 1);   // RNE
    return (ushort)(u >> 16);
}
__device__ __forceinline__ float b2f(ushort u) {
    return __builtin_bit_cast(float, (unsigned int)u << 16);
}
// Dekker-exact 3-way bf16 split: v = h + l + q2 + O(2^-27 v)
__device__ __forceinline__ void split3(float v, ushort& h, ushort& l, ushort& q2) {
    h = f2b(v); float r1 = v - b2f(h);
    l = f2b(r1); q2 = f2b(r1 - b2f(l));
}
// split 8 fp32 into 3 bf16x8 planes and store to LDS
__device__ __forceinline__ void split_store8(f32x4 a0, f32x4 a1, char* base,
                                             int planeStride, int off) {
    short8 h8, l8, q8;
#pragma unroll
    for (int i = 0; i < 4; ++i) {
        ushort h, l, q;
        split3(a0[i], h, l, q);
        h8[i] = (short)h; l8[i] = (short)l; q8[i] = (short)q;
    }
#pragma unroll
    for (int i = 0; i < 4; ++i) {
        ushort h, l, q;
        split3(a1[i], h, l, q);
        h8[4 + i] = (short)h; l8[4 + i] = (short)l; q8[4 + i] = (short)q;
    }
    *(short8*)(base + off) = h8;
    *(short8*)(base + planeStride + off) = l8;
    *(short8*)(base + 2 * planeStride + off) = q8;
}

// ---------- LayerNorm fp32 -> 3 bf16 planes (standalone, layer 0 only) -----
__global__ __launch_bounds__(256) void ln3_kernel(const float* __restrict__ x,
                                                  const float* __restrict__ g,
                                                  const float* __restrict__ bta,
                                                  ushort* __restrict__ out) {
    const int row = blockIdx.x;
    const int t = threadIdx.x;
    const float* xr = x + (size_t)row * DM;
    float v0 = xr[t], v1 = xr[t + 256];
    float s = v0 + v1, ss = v0 * v0 + v1 * v1;
    for (int o = 32; o; o >>= 1) {
        s += __shfl_down(s, o);
        ss += __shfl_down(ss, o);
    }
    __shared__ float ls[4], lss[4];
    const int wid = t >> 6, lane = t & 63;
    if (lane == 0) { ls[wid] = s; lss[wid] = ss; }
    __syncthreads();
    if (t == 0) {
        float S = ls[0] + ls[1] + ls[2] + ls[3];
        float SS = lss[0] + lss[1] + lss[2] + lss[3];
        float mu = S / DM;
        ls[0] = mu;
        lss[0] = SS / DM - mu * mu;
    }
    __syncthreads();
    const float mu = ls[0];
    const float r = rsqrtf(lss[0] + EPS);
    float o0 = (v0 - mu) * r * g[t] + bta[t];
    float o1 = (v1 - mu) * r * g[t + 256] + bta[t + 256];
    ushort h, l, q;
    size_t i0 = (size_t)row * DM + t;
    split3(o0, h, l, q);
    out[i0] = h; out[i0 + PS_HN] = l; out[i0 + 2 * PS_HN] = q;
    split3(o1, h, l, q);
    out[i0 + 256] = h; out[i0 + 256 + PS_HN] = l; out[i0 + 256 + 2 * PS_HN] = q;
}

// ---------- fused: split-K reduce + bias + residual(+tanh) + LN -> planes --
template <int KS, bool TANH>
__global__ __launch_bounds__(256) void redln_kernel(
    const float* __restrict__ P, long pstride, const float* __restrict__ bias,
    const float* __restrict__ X, float* __restrict__ Xout,
    const float* __restrict__ g, const float* __restrict__ bta,
    ushort* __restrict__ out) {
    const int row = blockIdx.x;
    const int t = threadIdx.x;
    const size_t e0 = (size_t)row * DM + t;
    const size_t e1 = e0 + 256;
    float a0 = P[e0], a1 = P[e1];
#pragma unroll
    for (int k = 1; k < KS; ++k) {
        a0 += P[(size_t)k * pstride + e0];
        a1 += P[(size_t)k * pstride + e1];
    }
    float v0 = X[e0] + a0 + bias[t];
    float v1 = X[e1] + a1 + bias[t + 256];
    if (TANH) { v0 = tanhf(v0); v1 = tanhf(v1); }
    Xout[e0] = v0;
    Xout[e1] = v1;
    float s = v0 + v1, ss = v0 * v0 + v1 * v1;
    for (int o = 32; o; o >>= 1) {
        s += __shfl_down(s, o);
        ss += __shfl_down(ss, o);
    }
    __shared__ float ls[4], lss[4];
    const int wid = t >> 6, lane = t & 63;
    if (lane == 0) { ls[wid] = s; lss[wid] = ss; }
    __syncthreads();
    if (t == 0) {
        float S = ls[0] + ls[1] + ls[2] + ls[3];
        float SS = lss[0] + lss[1] + lss[2] + lss[3];
        float mu = S / DM;
        ls[0] = mu;
        lss[0] = SS / DM - mu * mu;
    }
    __syncthreads();
    const float mu = ls[0];
    const float r = rsqrtf(lss[0] + EPS);
    float o0 = (v0 - mu) * r * g[t] + bta[t];
    float o1 = (v1 - mu) * r * g[t + 256] + bta[t + 256];
    ushort h, l, q;
    split3(o0, h, l, q);
    out[e0] = h; out[e0 + PS_HN] = l; out[e0 + 2 * PS_HN] = q;
    split3(o1, h, l, q);
    out[e1] = h; out[e1 + PS_HN] = l; out[e1 + 2 * PS_HN] = q;
}

// ---------- transpose weights: W[K][Nn] fp32 -> 3 bf16 planes of W^T[Nn][K] -
__global__ __launch_bounds__(256) void wtrans_kernel(const float* __restrict__ W,
                                                     ushort* __restrict__ WT,
                                                     int K, int Nn, long ps) {
    __shared__ float ts[32][33];
    const int n0 = blockIdx.x * 32, k0 = blockIdx.y * 32;
    const int tx = threadIdx.x & 31, ty = threadIdx.x >> 5;
#pragma unroll
    for (int p = 0; p < 4; ++p)
        ts[ty + p * 8][tx] = W[(size_t)(k0 + ty + p * 8) * Nn + n0 + tx];
    __syncthreads();
#pragma unroll
    for (int p = 0; p < 4; ++p) {
        float v = ts[tx][ty + p * 8];
        ushort h, l, q;
        split3(v, h, l, q);
        size_t idx = (size_t)(n0 + ty + p * 8) * K + k0 + tx;
        WT[idx] = h;
        WT[idx + ps] = l;
        WT[idx + 2 * ps] = q;
    }
}

// ---------- transpose V fp32 [4096][512] -> VTf fp32 [(b*H+h)*64+d][N] -----
__global__ __launch_bounds__(256) void vtrans_kernel(const float* __restrict__ v,
                                                     float* __restrict__ vt) {
    const int z = blockIdx.z, b = z >> 3, h = z & 7;
    __shared__ float ts[32][33];
    const int j0 = blockIdx.x * 32, d0 = blockIdx.y * 32;
    const int tx = threadIdx.x & 31, ty = threadIdx.x >> 5;
#pragma unroll
    for (int p = 0; p < 4; ++p)
        ts[ty + p * 8][tx] =
            v[(size_t)(b * N + j0 + ty + p * 8) * DM + h * 64 + d0 + tx];
    __syncthreads();
#pragma unroll
    for (int p = 0; p < 4; ++p)
        vt[(size_t)((b * H + h) * 64 + d0 + ty + p * 8) * N + j0 + tx] =
            ts[tx][ty + p * 8];
}

// ---------- 3-plane split MFMA GEMM (fp32-equivalent precision) ------------
// C = A[M,K] @ (Bt[Nn,K])^T. A/B pre-split 3-plane bf16 or fp32 with on-the-
// fly Dekker split (AF32/BF32). 6 MFMA terms, small first.
// z decomposes: zo = z/ZDIV (A/B/C-outer offsets), zk = z%ZDIV (k-chunk;
// partials at zk*zCk).
// EPI: 0 plain->f32, 1 scale->f32, 2 bias+gelu->f32, 3 qkv col-branch->f32
template <int BM, int BN, int WR, int WC, int EPI, bool AF32, bool BF32, int ZDIV>
__global__ __launch_bounds__(256) void mm3_kernel(
    const void* __restrict__ Av, int sA, long pA, long zA,
    const void* __restrict__ Bv, int sB, long pB, long zB,
    const float* __restrict__ bias, const float* __restrict__ res,
    void* __restrict__ Cv, int sC, long zC, long zCk, int K, float scale) {
    constexpr int WM = BM / WR, WN = BN / WC;
    constexpr int FM = WM / 16, FN = WN / 16;
    constexpr int RA = BM / 64, RB = BN / 64;
    static_assert(!AF32 || RA <= 2, "AF32 assumes BM<=128");
    static_assert(!BF32 || RB <= 2, "BF32 assumes BN<=128");
    int bx, by, z;
    {
        const int gx = gridDim.x, gy = gridDim.y;
        const long nwg = (long)gx * gy * gridDim.z;
        long o = ((long)blockIdx.z * gy + blockIdx.y) * gx + blockIdx.x;
        if ((nwg & 7) == 0) { const long q = nwg >> 3; o = (o & 7) * q + (o >> 3); }
        bx = (int)(o % gx);
        const long r1 = o / gx;
        by = (int)(r1 % gy);
        z  = (int)(r1 / gy);
    }
    const int zo = z / ZDIV, zk = z % ZDIV;
    const ushort* A  = AF32 ? nullptr : (const ushort*)Av + (size_t)zo * zA;
    const float*  Af = AF32 ? (const float*)Av + (size_t)zo * zA : nullptr;
    const ushort* Bt = BF32 ? nullptr : (const ushort*)Bv + (size_t)zo * zB;
    const float*  Bf = BF32 ? (const float*)Bv + (size_t)zo * zB : nullptr;
    __shared__ char lds[3 * (BM + BN) * 64];
    char* Bbase = lds + 3 * BM * 64;
    const int t = threadIdx.x;
    const int lane = t & 63, w = t >> 6;
    const int wr = w / WC, wc = w % WC;
    const int m0 = by * BM, n0 = bx * BN;
    const int sr = t >> 2, skg = t & 3;
    const int off0 = sr * 64 + 16 * (skg ^ ((sr >> 1) & 3));

    f32x4 acc[FM][FN];
#pragma unroll
    for (int i = 0; i < FM; ++i)
#pragma unroll
        for (int j = 0; j < FN; ++j) acc[i][j] = (f32x4){0.f, 0.f, 0.f, 0.f};

    u32x4 cA[3][RA], nA[3][RA], cB[3][RB], nB[3][RB];
    f32x4 cAf[2 * RA], nAf[2 * RA], cBf[2 * RB], nBf[2 * RB];

    auto loadAll = [&](int KT, u32x4 (&DA)[3][RA], f32x4 (&DAf)[2 * RA],
                       u32x4 (&DB)[3][RB], f32x4 (&DBf)[2 * RB]) {
        if constexpr (AF32) {
#pragma unroll
            for (int p = 0; p < RA; ++p) {
                const float* s_ = Af + (size_t)(m0 + sr + p * 64) * sA + KT + skg * 8;
                DAf[2 * p] = *(const f32x4*)s_;
                DAf[2 * p + 1] = *(const f32x4*)(s_ + 4);
            }
        } else {
#pragma unroll
            for (int pl = 0; pl < 3; ++pl)
#pragma unroll
                for (int p = 0; p < RA; ++p)
                    DA[pl][p] = *(const u32x4*)(A + (size_t)pl * pA +
                        (size_t)(m0 + sr + p * 64) * sA + KT + skg * 8);
        }
        if constexpr (BF32) {
#pragma unroll
            for (int p = 0; p < RB; ++p) {
                const float* s_ = Bf + (size_t)(n0 + sr + p * 64) * sB + KT + skg * 8;
                DBf[2 * p] = *(const f32x4*)s_;
                DBf[2 * p + 1] = *(const f32x4*)(s_ + 4);
            }
        } else {
#pragma unroll
            for (int pl = 0; pl < 3; ++pl)
#pragma unroll
                for (int p = 0; p < RB; ++p)
                    DB[pl][p] = *(const u32x4*)(Bt + (size_t)pl * pB +
                        (size_t)(n0 + sr + p * 64) * sB + KT + skg * 8);
        }
    };
    auto storeAll = [&](u32x4 (&DA)[3][RA], f32x4 (&DAf)[2 * RA],
                        u32x4 (&DB)[3][RB], f32x4 (&DBf)[2 * RB]) {
        if constexpr (AF32) {
#pragma unroll
            for (int p = 0; p < RA; ++p)
                split_store8(DAf[2 * p], DAf[2 * p + 1], lds, BM * 64,
                             p * 4096 + off0);
        } else {
#pragma unroll
            for (int pl = 0; pl < 3; ++pl)
#pragma unroll
                for (int p = 0; p < RA; ++p)
                    *(u32x4*)(lds + pl * BM * 64 + p * 4096 + off0) = DA[pl][p];
        }
        if constexpr (BF32) {
#pragma unroll
            for (int p = 0; p < RB; ++p)
                split_store8(DBf[2 * p], DBf[2 * p + 1], Bbase, BN * 64,
                             p * 4096 + off0);
        } else {
#pragma unroll
            for (int pl = 0; pl < 3; ++pl)
#pragma unroll
                for (int p = 0; p < RB; ++p)
                    *(u32x4*)(Bbase + pl * BN * 64 + p * 4096 + off0) = DB[pl][p];
        }
    };

    const int Kc = K / ZDIV;
    const int kbeg = zk * Kc;
    loadAll(kbeg, cA, cAf, cB, cBf);
    for (int kt = kbeg; kt < kbeg + Kc; kt += 32) {
        __syncthreads();
        storeAll(cA, cAf, cB, cBf);
        if (kt + 32 < kbeg + Kc) loadAll(kt + 32, nA, nAf, nB, nBf);
        __syncthreads();
        short8 af[3][FM], bf[3][FN];
        const int kg = lane >> 4;
#pragma unroll
        for (int pl = 0; pl < 3; ++pl)
#pragma unroll
            for (int i = 0; i < FM; ++i) {
                const int r = wr * WM + i * 16 + (lane & 15);
                af[pl][i] = *(const short8*)(lds + pl * BM * 64 + r * 64 +
                                             16 * (kg ^ ((r >> 1) & 3)));
            }
#pragma unroll
        for (int pl = 0; pl < 3; ++pl)
#pragma unroll
            for (int j = 0; j < FN; ++j) {
                const int r = wc * WN + j * 16 + (lane & 15);
                bf[pl][j] = *(const short8*)(Bbase + pl * BN * 64 + r * 64 +
                                             16 * (kg ^ ((r >> 1) & 3)));
            }
        // small terms first: s=2 (hq,ll,qh), s=1 (hl,lh), s=0 (hh)
#pragma unroll
        for (int i = 0; i < FM; ++i)
#pragma unroll
            for (int j = 0; j < FN; ++j)
#pragma unroll
                for (int s = 2; s >= 0; --s)
#pragma unroll
                    for (int ph = 0; ph <= 2; ++ph) {
                        const int pb = s - ph;
                        if (pb < 0 || pb > 2) continue;
                        acc[i][j] = __builtin_amdgcn_mfma_f32_16x16x32_bf16(
                            af[ph][i], bf[pb][j], acc[i][j], 0, 0, 0);
                    }
        if constexpr (AF32) {
#pragma unroll
            for (int p = 0; p < 2 * RA; ++p) cAf[p] = nAf[p];
        } else {
#pragma unroll
            for (int pl = 0; pl < 3; ++pl)
#pragma unroll
                for (int p = 0; p < RA; ++p) cA[pl][p] = nA[pl][p];
        }
        if constexpr (BF32) {
#pragma unroll
            for (int p = 0; p < 2 * RB; ++p) cBf[p] = nBf[p];
        } else {
#pragma unroll
            for (int pl = 0; pl < 3; ++pl)
#pragma unroll
                for (int p = 0; p < RB; ++p) cB[pl][p] = nB[pl][p];
        }
    }
    float* Cbase = (float*)Cv + (size_t)zo * zC + (size_t)zk * zCk;
#pragma unroll
    for (int i = 0; i < FM; ++i) {
#pragma unroll
        for (int j = 0; j < FN; ++j) {
            const int col = n0 + wc * WN + j * 16 + (lane & 15);
#pragma unroll
            for (int r4 = 0; r4 < 4; ++r4) {
                const int row = m0 + wr * WM + i * 16 + (lane >> 4) * 4 + r4;
                float v = acc[i][j][r4];
                if (EPI == 1) v *= scale;
                if (EPI == 2) {
                    v += bias[col];
                    v = 0.5f * v * (1.0f + erff(v * 0.70710678118654752f));
                }
                if (EPI == 3) {
                    if (col < 1024)
                        ((float*)Cv)[(size_t)row * 1024 + col] = v;
                    else
                        const_cast<float*>(res)[(size_t)row * 512 + col - 1024] = v;
                } else {
                    Cbase[(size_t)row * sC + col] = v;
                }
            }
        }
    }
}

// ---------- partial reduce: MODE 0: out=ΣP; 2: out=tanh(X+ΣP+bias) ---------
template <int KS, int MODE>
__global__ __launch_bounds__(256) void red_kernel(const float* __restrict__ P,
                                                  long pstride,
                                                  const float* __restrict__ bias,
                                                  const float* __restrict__ X,
                                                  float* __restrict__ out) {
    const size_t e = ((size_t)blockIdx.x * 256 + threadIdx.x) * 4;
    f32x4 a = *(const f32x4*)(P + e);
#pragma unroll
    for (int k = 1; k < KS; ++k) {
        f32x4 pk = *(const f32x4*)(P + (size_t)k * pstride + e);
#pragma unroll
        for (int i = 0; i < 4; ++i) a[i] += pk[i];
    }
    if (MODE >= 1) {
        f32x4 xb = *(const f32x4*)(X + e);
        f32x4 bb = *(const f32x4*)(bias + (e & (DM - 1)));
#pragma unroll
        for (int i = 0; i < 4; ++i) {
            float r = xb[i] + a[i] + bb[i];
            a[i] = (MODE == 2) ? tanhf(r) : r;
        }
    }
    *(f32x4*)(out + e) = a;
}

// ---------- softmax (max-subtract) + head mix + head-LN, fp32, vectorized --
__global__ __launch_bounds__(256) void softmax_mix_kernel(float* __restrict__ d,
                                                          const float* __restrict__ rw,
                                                          const float* __restrict__ rg,
                                                          const float* __restrict__ rb) {
    const int i = blockIdx.x;
    const int t = threadIdx.x;
    const int lane = t & 63, wid = t >> 6;
    __shared__ float red[4];
    __shared__ float srw[64], srg[8], srb[8];
    if (t < 64) srw[t] = rw[t];
    if (t < 8) { srg[t] = rg[t]; srb[t] = rb[t]; }
    f32x4 p[8];
#pragma unroll
    for (int h = 0; h < 8; ++h) {
        p[h] = ((const f32x4*)(d + ((size_t)h * 1024 + i) * 1024))[t];
        float lm = fmaxf(fmaxf(p[h][0], p[h][1]), fmaxf(p[h][2], p[h][3]));
        for (int o = 32; o; o >>= 1) lm = fmaxf(lm, __shfl_down(lm, o));
        __syncthreads();
        if (lane == 0) red[wid] = lm;
        __syncthreads();
        const float M = fmaxf(fmaxf(red[0], red[1]), fmaxf(red[2], red[3]));
        float ls = 0.f;
#pragma unroll
        for (int u = 0; u < 4; ++u) {
            p[h][u] = expf(p[h][u] - M);
            ls += p[h][u];
        }
        for (int o = 32; o; o >>= 1) ls += __shfl_down(ls, o);
        __syncthreads();
        if (lane == 0) red[wid] = ls;
        __syncthreads();
        const float inv = 1.0f / (red[0] + red[1] + red[2] + red[3]);
#pragma unroll
        for (int u = 0; u < 4; ++u) p[h][u] *= inv;
    }
    f32x4 mg[8];
#pragma unroll
    for (int g = 0; g < 8; ++g) {
#pragma unroll
        for (int u = 0; u < 4; ++u) {
            float acc = 0.f;
#pragma unroll
            for (int h = 0; h < 8; ++h) acc += p[h][u] * srw[h * 8 + g];
            mg[g][u] = acc;
        }
    }
#pragma unroll
    for (int u = 0; u < 4; ++u) {
        float mean = 0.f;
#pragma unroll
        for (int g = 0; g < 8; ++g) mean += mg[g][u];
        mean *= 0.125f;
        float var = 0.f;
#pragma unroll
        for (int g = 0; g < 8; ++g) { float dd = mg[g][u] - mean; var += dd * dd; }
        var *= 0.125f;
        const float rs = rsqrtf(var + EPS);
#pragma unroll
        for (int g = 0; g < 8; ++g) mg[g][u] = (mg[g][u] - mean) * rs * srg[g] + srb[g];
    }
#pragma unroll
    for (int g = 0; g < 8; ++g)
        ((f32x4*)(d + ((size_t)g * 1024 + i) * 1024))[t] = mg[g];
}

extern "C" void kernel_launch(void* const* d_in, const int* in_sizes, int n_in,
                              void* d_out, int out_size, void* d_ws, size_t ws_size,
                              hipStream_t stream) {
    const float* x_in  = (const float*)d_in[0];
    const float* ln1_g = (const float*)d_in[1];
    const float* ln1_b = (const float*)d_in[2];
    const float* w_qkv = (const float*)d_in[3];
    const float* re_w  = (const float*)d_in[4];
    const float* rln_g = (const float*)d_in[5];
    const float* rln_b = (const float*)d_in[6];
    const float* w_out = (const float*)d_in[7];
    const float* b_out = (const float*)d_in[8];
    const float* ln2_g = (const float*)d_in[9];
    const float* ln2_b = (const float*)d_in[10];
    const float* w1    = (const float*)d_in[11];
    const float* b1    = (const float*)d_in[12];
    const float* w2    = (const float*)d_in[13];
    const float* b2    = (const float*)d_in[14];

    // 80 MB, phase-aliased (byte-exact extents in MB):
    // X[0,8) QKf[8,24) VTf[24,32) D[32,64) AO[64,72) PVP[72,80)
    // HN3[48,60) (ln1 planes; live from redln/ln3 until qkv reads it)
    // WQT[40,44.5) (attn transient; clobbered by D in b-loop — dead by then)
    // Vf[32,40) (dead after vtrans) WOT[32,33.5) OPP[34,50) (post-b-loop)
    // HN3f[8,20) W1T[20,26) W2T[40,46) HIDf[48,80) FPP[8,40) (ffn phase)
    char* wsb = (char*)d_ws;
    float*  X    = (float*)wsb;
    float*  QKf  = (float*)(wsb + (8ull << 20));
    ushort* HN3f = (ushort*)(wsb + (8ull  << 20));
    float*  FPP  = (float*)(wsb + (8ull  << 20));
    ushort* W1T  = (ushort*)(wsb + (20ull << 20));
    float*  VTf  = (float*)(wsb + (24ull << 20));
    float*  D    = (float*)(wsb + (32ull << 20));
    float*  Vf   = (float*)(wsb + (32ull << 20));
    ushort* WOT  = (ushort*)(wsb + (32ull << 20));
    float*  OPP  = (float*)(wsb + (34ull << 20));
    ushort* W2T  = (ushort*)(wsb + (40ull << 20));
    ushort* WQT  = (ushort*)(wsb + (40ull << 20));   // [40, 44.5) — clear of HN3
    ushort* HN3  = (ushort*)(wsb + (48ull << 20));
    float*  HIDf = (float*)(wsb + (48ull << 20));
    float*  AO   = (float*)(wsb + (64ull << 20));
    float*  PVP  = (float*)(wsb + (72ull << 20));

    hipMemcpyAsync(X, x_in, sizeof(float) * (size_t)TOK * DM,
                   hipMemcpyDeviceToDevice, stream);

    for (int l = 0; l < 4; ++l) {
        // ======== attention ========
        if (l == 0)
            ln3_kernel<<<TOK, 256, 0, stream>>>(X, ln1_g, ln1_b, HN3);
        wtrans_kernel<<<dim3(QKVW / 32, DM / 32), 256, 0, stream>>>(
            w_qkv + (size_t)l * DM * QKVW, WQT, DM, QKVW, PS_WQ);
        // qkv -> QKf [4096][1024] + Vf [4096][512], fp32
        mm3_kernel<128, 128, 2, 2, 3, false, false, 1>
            <<<dim3(12, TOK / 128, 1), 256, 0, stream>>>(
            HN3, DM, PS_HN, 0, WQT, DM, PS_WQ, 0, nullptr, Vf,
            QKf, 1024, 0, 0, DM, 1.f);
        vtrans_kernel<<<dim3(N / 32, 2, B * H), 256, 0, stream>>>(Vf, VTf);

        for (int b = 0; b < B; ++b) {
            const float* qb = QKf + (size_t)b * N * 1024;
            // dots (scaled) -> D [H][1024][1024] fp32; 64x64 tiles, z = head
            mm3_kernel<64, 64, 2, 2, 1, true, true, 1>
                <<<dim3(16, 16, H), 256, 0, stream>>>(
                qb, 1024, 0, 64, qb + 512, 1024, 0, 64, nullptr, nullptr,
                D, 1024, (long)1024 * 1024, 0, 64, SCALE);
            softmax_mix_kernel<<<N, 256, 0, stream>>>(
                D, re_w + l * H * H, rln_g + l * H, rln_b + l * H);
            // PV 64x64 split-K x4 -> PVP; z = head*4 + kchunk
            mm3_kernel<64, 64, 2, 2, 0, true, true, 4>
                <<<dim3(1, 16, H * 4), 256, 0, stream>>>(
                D, 1024, 0, (long)1024 * 1024,
                VTf + (size_t)b * H * 64 * N, 1024, 0, (long)64 * N,
                nullptr, nullptr,
                PVP, DM, 64, (long)N * DM, N, 1.f);
            red_kernel<4, 0><<<N * DM / 1024, 256, 0, stream>>>(
                PVP, (long)N * DM, nullptr, nullptr, AO + (size_t)b * N * DM);
        }
        // out-proj split-K 2 -> OPP, then fused X += OPP+bias & ln2 -> HN3f
        wtrans_kernel<<<dim3(DM / 32, DM / 32), 256, 0, stream>>>(
            w_out + (size_t)l * DM * DM, WOT, DM, DM, (long)DM * DM);
        mm3_kernel<64, 128, 1, 4, 0, true, false, 2>
            <<<dim3(4, TOK / 64, 2), 256, 0, stream>>>(
            AO, DM, 0, 0, WOT, DM, (long)DM * DM, 0, nullptr, nullptr,
            OPP, DM, 0, (long)TOK * DM, DM, 1.f);
        redln_kernel<2, false><<<TOK, 256, 0, stream>>>(
            OPP, (long)TOK * DM, b_out + l * DM, X, X,
            ln2_g + l * DM, ln2_b + l * DM, HN3f);

        // ======== ffn ========
        wtrans_kernel<<<dim3(MLP / 32, DM / 32), 256, 0, stream>>>(
            w1 + (size_t)l * DM * MLP, W1T, DM, MLP, (long)MLP * DM);
        mm3_kernel<128, 128, 2, 2, 2, false, false, 1>
            <<<dim3(MLP / 128, TOK / 128, 1), 256, 0, stream>>>(
            HN3f, DM, PS_HN, 0, W1T, DM, (long)MLP * DM, 0, b1 + l * MLP, nullptr,
            HIDf, MLP, 0, 0, DM, 1.f);
        wtrans_kernel<<<dim3(DM / 32, MLP / 32), 256, 0, stream>>>(
            w2 + (size_t)l * MLP * DM, W2T, MLP, DM, (long)DM * MLP);
        // ffn2 split-K 4 -> FPP
        mm3_kernel<128, 128, 2, 2, 0, true, false, 4>
            <<<dim3(4, TOK / 128, 4), 256, 0, stream>>>(
            HIDf, MLP, 0, 0, W2T, MLP, (long)DM * MLP, 0, nullptr, nullptr,
            FPP, DM, 0, (long)TOK * DM, MLP, 1.f);
        if (l < 3) {
            // fused: X = tanh(X + ΣFPP + bias) & ln1(l+1) -> HN3
            redln_kernel<4, true><<<TOK, 256, 0, stream>>>(
                FPP, (long)TOK * DM, b2 + l * DM, X, X,
                ln1_g + (l + 1) * DM, ln1_b + (l + 1) * DM, HN3);
        } else {
            red_kernel<4, 2><<<TOK * DM / 1024, 256, 0, stream>>>(
                FPP, (long)TOK * DM, b2 + l * DM, X, (float*)d_out);
        }
    }
}